// Round 1
// baseline (1899.480 us; speedup 1.0000x reference)
//
#include <hip/hip_runtime.h>

#define L_ 28
#define E_ 1024
#define H_ 8
#define D_ 128
#define B_ 2
#define S_ 1024

typedef __bf16 bf16x8 __attribute__((ext_vector_type(8)));
typedef float f32x4 __attribute__((ext_vector_type(4)));

// pack two fp32 -> two bf16 (RNE), low = a, high = b
__device__ __forceinline__ unsigned int f2bf2(float a, float b) {
  unsigned int ua = __builtin_bit_cast(unsigned int, a);
  ua += 0x7fffu + ((ua >> 16) & 1u);
  unsigned int ub = __builtin_bit_cast(unsigned int, b);
  ub += 0x7fffu + ((ub >> 16) & 1u);
  return (ua >> 16) | (ub & 0xffff0000u);
}

// Fused: scale -> rmsnorm(ln_w) -> K/V projection (bf16 MFMA) -> k-rmsnorm -> RoPE
// Grid: 28 layers * 16 m-tiles * 8 n-tiles; block 256 = 4 waves, each wave 32 rows x 128 cols.
__global__ __launch_bounds__(256, 2) void fused_kv_kernel(
    const float* __restrict__ x,        // (B*S, E) image_context
    const float* __restrict__ scales,   // (L)
    const float* __restrict__ lnw,      // (L, E)
    const float* __restrict__ Wk,       // (L, E, E) [l][kcol][e]
    const float* __restrict__ Wv,       // (L, E, E)
    const float* __restrict__ knw,      // (L, D)
    float* __restrict__ out)            // (2, L, B, H, S, D) fp32
{
  // +8 bf16 pad per row: 144B stride -> 2-way LDS bank aliasing only (free)
  __shared__ unsigned short sA[128][72];
  __shared__ unsigned short sK[128][72];
  __shared__ unsigned short sV[128][72];
  __shared__ float s_lnw[E_];
  __shared__ float s_knw[D_];
  __shared__ float s_sumsq[128];

  const int t = threadIdx.x;
  const int bx = blockIdx.x;
  const int l = bx >> 7;               // 128 blocks per layer
  const int n_idx = (bx >> 4) & 7;     // head index (tile width 128 == D)
  const int m_idx = bx & 15;           // 16 adjacent m-blocks share the same W slice (L2)
  const int m_base = m_idx * 128;
  const int n_base = n_idx * 128;

  // preload per-layer norm weights
  *reinterpret_cast<float4*>(&s_lnw[t * 4]) =
      *reinterpret_cast<const float4*>(&lnw[(size_t)l * E_ + t * 4]);
  if (t < D_) s_knw[t] = knw[l * D_ + t];

  // staging mapping: c4 = float4 column (16 cover BK=64), r0 = row group; each
  // thread owns rows r0+16p for p=0..7 across ALL k-steps -> private sumsq partials
  const int c4 = t & 15;
  const int r0 = t >> 4;

  const float* xg  = x  + (size_t)(m_base + r0) * E_ + c4 * 4;
  const float* wkg = Wk + (size_t)l * E_ * E_ + (size_t)(n_base + r0) * E_ + c4 * 4;
  const float* wvg = Wv + (size_t)l * E_ * E_ + (size_t)(n_base + r0) * E_ + c4 * 4;

  const int lane = t & 63;
  const int wv = t >> 6;               // wave id: rows [wv*32, wv*32+32)
  const int col16 = lane & 15;
  const int quad = lane >> 4;

  f32x4 accK[2][8], accV[2][8];
  #pragma unroll
  for (int i = 0; i < 2; ++i)
    #pragma unroll
    for (int j = 0; j < 8; ++j) {
      accK[i][j] = (f32x4){0.f, 0.f, 0.f, 0.f};
      accV[i][j] = (f32x4){0.f, 0.f, 0.f, 0.f};
    }
  float sq[8] = {0.f, 0.f, 0.f, 0.f, 0.f, 0.f, 0.f, 0.f};

  for (int ks = 0; ks < 16; ++ks) {
    const int k0 = ks * 64;
    // A loads issue before the barrier (overlap previous MFMA tail)
    float4 av[8];
    #pragma unroll
    for (int p = 0; p < 8; ++p)
      av[p] = *reinterpret_cast<const float4*>(xg + (size_t)(p * 16) * E_ + k0);

    __syncthreads();  // previous iteration's LDS reads complete

    #pragma unroll
    for (int p = 0; p < 8; ++p) {
      sq[p] += av[p].x * av[p].x + av[p].y * av[p].y +
               av[p].z * av[p].z + av[p].w * av[p].w;   // raw x row sumsq
      uint2 pk;
      pk.x = f2bf2(av[p].x, av[p].y);
      pk.y = f2bf2(av[p].z, av[p].w);
      *reinterpret_cast<uint2*>(&sA[r0 + p * 16][c4 * 4]) = pk;
    }
    // fold ln_w (reduction-dim weight) into W tiles at staging time
    const float4 lw = *reinterpret_cast<const float4*>(&s_lnw[k0 + c4 * 4]);
    #pragma unroll
    for (int p = 0; p < 8; ++p) {
      float4 w4 = *reinterpret_cast<const float4*>(wkg + (size_t)(p * 16) * E_ + k0);
      uint2 pk;
      pk.x = f2bf2(w4.x * lw.x, w4.y * lw.y);
      pk.y = f2bf2(w4.z * lw.z, w4.w * lw.w);
      *reinterpret_cast<uint2*>(&sK[r0 + p * 16][c4 * 4]) = pk;
    }
    #pragma unroll
    for (int p = 0; p < 8; ++p) {
      float4 w4 = *reinterpret_cast<const float4*>(wvg + (size_t)(p * 16) * E_ + k0);
      uint2 pk;
      pk.x = f2bf2(w4.x * lw.x, w4.y * lw.y);
      pk.y = f2bf2(w4.z * lw.z, w4.w * lw.w);
      *reinterpret_cast<uint2*>(&sV[r0 + p * 16][c4 * 4]) = pk;
    }
    __syncthreads();

    #pragma unroll
    for (int kk = 0; kk < 2; ++kk) {
      const int ko = kk * 32 + quad * 8;
      bf16x8 a0 = *reinterpret_cast<const bf16x8*>(&sA[wv * 32 + col16][ko]);
      bf16x8 a1 = *reinterpret_cast<const bf16x8*>(&sA[wv * 32 + 16 + col16][ko]);
      #pragma unroll
      for (int nt = 0; nt < 8; ++nt) {
        bf16x8 bk = *reinterpret_cast<const bf16x8*>(&sK[nt * 16 + col16][ko]);
        accK[0][nt] = __builtin_amdgcn_mfma_f32_16x16x32_bf16(a0, bk, accK[0][nt], 0, 0, 0);
        accK[1][nt] = __builtin_amdgcn_mfma_f32_16x16x32_bf16(a1, bk, accK[1][nt], 0, 0, 0);
        bf16x8 bv = *reinterpret_cast<const bf16x8*>(&sV[nt * 16 + col16][ko]);
        accV[0][nt] = __builtin_amdgcn_mfma_f32_16x16x32_bf16(a0, bv, accV[0][nt], 0, 0, 0);
        accV[1][nt] = __builtin_amdgcn_mfma_f32_16x16x32_bf16(a1, bv, accV[1][nt], 0, 0, 0);
      }
    }
  }

  // reduce per-row sumsq of x (16 partials per row) via LDS scratch aliased on sA
  __syncthreads();
  float* red = reinterpret_cast<float*>(&sA[0][0]);  // 128*16 fp32 = 8KB <= sA
  #pragma unroll
  for (int p = 0; p < 8; ++p) red[(r0 + p * 16) * 16 + c4] = sq[p];
  __syncthreads();
  if (t < 128) {
    float s = 0.f;
    #pragma unroll
    for (int i = 0; i < 16; ++i) s += red[t * 16 + i];
    s_sumsq[t] = s;
  }
  __syncthreads();

  // ---- epilogue: rho, k-rmsnorm (per head row, 16-lane shuffle), RoPE, store ----
  const float scale = scales[l];
  float freq[8], kw8[8];
  #pragma unroll
  for (int nt = 0; nt < 8; ++nt) {
    const int d = nt * 16 + col16;
    // theta^(-(d%64)/64) = exp2(-(d%64) * log2(1e6)/64)
    freq[nt] = exp2f(-(float)(d & 63) * 0.31143075889569023f);
    kw8[nt] = s_knw[d];
  }
  const size_t VOFF = (size_t)L_ * B_ * H_ * S_ * D_;

  #pragma unroll
  for (int mt = 0; mt < 2; ++mt) {
    #pragma unroll
    for (int reg = 0; reg < 4; ++reg) {
      const int rl = wv * 32 + mt * 16 + quad * 4 + reg;  // C-layout row
      const int mg = m_base + rl;
      const int bb = mg >> 10;      // batch
      const int ss = mg & 1023;     // sequence position
      const float ms = s_sumsq[rl] * (1.0f / 1024.0f);
      const float rho = scale * rsqrtf(scale * scale * ms + 1e-6f);
      float kvv[8], vvv[8];
      float ksum = 0.f;
      #pragma unroll
      for (int nt = 0; nt < 8; ++nt) {
        kvv[nt] = rho * accK[mt][nt][reg];
        vvv[nt] = rho * accV[mt][nt][reg];
        ksum += kvv[nt] * kvv[nt];
      }
      // row covers 128 cols across 16 lanes (same quad): butterfly over low 4 bits
      #pragma unroll
      for (int off = 1; off < 16; off <<= 1) ksum += __shfl_xor(ksum, off, 64);
      const float r2 = rsqrtf(ksum * (1.0f / 128.0f) + 1e-6f);
      float kn[8];
      #pragma unroll
      for (int nt = 0; nt < 8; ++nt) kn[nt] = kvv[nt] * r2 * kw8[nt];
      const float sf = (float)ss;
      const size_t base = ((((size_t)(l * B_ + bb)) * H_ + n_idx) * S_ + ss) * D_;
      #pragma unroll
      for (int nt = 0; nt < 8; ++nt) {
        const float ang = sf * freq[nt];
        const float cs = __cosf(ang);
        const float sn = __sinf(ang);
        // rotate_half: d<64 -> -k[d+64] (nt+4), d>=64 -> +k[d-64] (nt-4); same lane
        const float rot = (nt < 4) ? -kn[nt + 4] : kn[nt - 4];
        out[base + nt * 16 + col16] = kn[nt] * cs + rot * sn;
        out[VOFF + base + nt * 16 + col16] = vvv[nt];
      }
    }
  }
}

extern "C" void kernel_launch(void* const* d_in, const int* in_sizes, int n_in,
                              void* d_out, int out_size, void* d_ws, size_t ws_size,
                              hipStream_t stream) {
  const float* x      = (const float*)d_in[0];
  const float* scales = (const float*)d_in[1];
  const float* lnw    = (const float*)d_in[2];
  const float* Wk     = (const float*)d_in[3];
  const float* Wv     = (const float*)d_in[4];
  const float* knw    = (const float*)d_in[5];
  float* out = (float*)d_out;
  dim3 grid(L_ * 16 * 8);  // 3584 blocks
  fused_kv_kernel<<<grid, 256, 0, stream>>>(x, scales, lnw, Wk, Wv, knw, out);
}